// Round 7
// baseline (146.378 us; speedup 1.0000x reference)
//
#include <hip/hip_runtime.h>

// ---------------------------------------------------------------------------
// GraphSAGE 2-layer forward, bf16 MFMA, split pipeline:
//   pack_w -> agg0_stream (wave-per-row mean + self cast) -> gemm0 -> agg1 -> gemm1
// Segments (rows): src0 256, src1 2560, dst0 256, dst1 2560, neg0 1280, neg1 12800
// A1/H1 row offsets: src0@0 src1@256 dst0@2816 dst1@3072 neg0@5632 neg1@6912, tot 19712
// A1 [19712][1024] bf16: cols [0,512)=self(500+12 pad), [512,1024)=mean(500+12 pad)
// ---------------------------------------------------------------------------

typedef __attribute__((ext_vector_type(8))) short bhalf8;
typedef __attribute__((ext_vector_type(4))) float floatx4;

__device__ __forceinline__ ushort f2bf(float f) {
  uint32_t u = __float_as_uint(f);
  return (ushort)((u + 0x7fffu + ((u >> 16) & 1u)) >> 16);
}
__device__ __forceinline__ float bf2f(ushort u) {
  return __uint_as_float(((uint32_t)u) << 16);
}
__device__ __forceinline__ void gll16(const void* g, void* l) {
  __builtin_amdgcn_global_load_lds((const __attribute__((address_space(1))) void*)g,
                                   (__attribute__((address_space(3))) void*)l, 16, 0, 0);
}

// ------- W pack. Grid: 1280 blocks exact. -----------------------------------
// W0p: [kstp(32)][kg(4)][n(256)][i(8)]; k<512 -> W0 row k (<500 valid),
//      k>=512 -> W0 row 500+(k-512) (<500 valid), else 0.
// W1p: [kstp(16)][kg(4)][n(128)][i(8)], K=512.
__global__ __launch_bounds__(256) void pack_w(const float* __restrict__ W0, const float* __restrict__ W1,
                                              ushort* __restrict__ W0p, ushort* __restrict__ W1p) {
  const int idx = blockIdx.x * 256 + threadIdx.x;
  if (idx < 262144) {
    const int i = idx & 7, n = (idx >> 3) & 255, kgv = (idx >> 11) & 3, kstp = idx >> 13;
    const int k = kstp * 32 + kgv * 8 + i;
    int srcr;
    if (k < 512) srcr = (k < 500) ? k : -1;
    else { const int k2 = k - 512; srcr = (k2 < 500) ? 500 + k2 : -1; }
    W0p[idx] = (srcr >= 0) ? f2bf(W0[srcr * 256 + n]) : (ushort)0;
  } else {
    const int j = idx - 262144;
    const int i = j & 7, n = (j >> 3) & 127, kgv = (j >> 10) & 3, kstp = j >> 12;
    const int k = kstp * 32 + kgv * 8 + i;
    W1p[j] = f2bf(W1[k * 128 + n]);
  }
}

// ------- agg0: grid 6160 blocks. b<1232: self-cast (16 rows/blk).
//         b>=1232: mean-of-10, wave-per-row (4 rows/blk), lane owns cols l, l+64.
struct AggP {
  const float* selfp[6];
  const float* neigh[6];
  int selfEnd[6];  // {16,176,192,352,432,1232}
  int meanEnd[6];  // {1296,1360,1680,2320,2960,6160}  (seg order 0,2,4,1,3,5)
  int meanSeg[6];  // {0,2,4,1,3,5}
  int outRow[6];   // {0,256,2816,3072,5632,6912}
};

__global__ __launch_bounds__(256) void agg0_stream(AggP P, ushort* __restrict__ A1) {
  const int b = blockIdx.x, tid = threadIdx.x;
  ushort4* __restrict__ A1v = (ushort4*)A1;
  if (b < 1232) {
    // ---- self mode ----
    int s = 0;
#pragma unroll
    for (int t = 0; t < 5; ++t) s = (b >= P.selfEnd[t]) ? t + 1 : s;
    const int base = s ? P.selfEnd[s - 1] : 0;
    const int r0 = (b - base) * 16;
    const int rr = tid >> 7, c = tid & 127;
    const bool valid = c < 125;
    const int cc = valid ? c : 0;
    const floatx4* __restrict__ S = (const floatx4*)P.selfp[s];
    const long og = (long)P.outRow[s];
    floatx4 v[8];
#pragma unroll
    for (int i = 0; i < 8; ++i) v[i] = S[(long)(r0 + rr * 8 + i) * 125 + cc];
#pragma unroll
    for (int i = 0; i < 8; ++i) {
      floatx4 x = v[i];
      if (!valid) x = (floatx4){0.f, 0.f, 0.f, 0.f};
      ushort4 o;
      o.x = f2bf(x.x); o.y = f2bf(x.y); o.z = f2bf(x.z); o.w = f2bf(x.w);
      A1v[(og + r0 + rr * 8 + i) * 256 + c] = o;
    }
  } else {
    // ---- mean mode ----
    int s = P.meanSeg[0], base = 1232;
#pragma unroll
    for (int t = 0; t < 5; ++t) {
      const bool g = b >= P.meanEnd[t];
      s = g ? P.meanSeg[t + 1] : s;
      base = g ? P.meanEnd[t] : base;
    }
    const int r = (b - base) * 4 + (tid >> 6);
    const int lane = tid & 63;
    const floatx4* __restrict__ Ng = (const floatx4*)P.neigh[s] + (long)r * 1250;
    const int c2 = lane + 64;
    const bool v2 = c2 < 125;
    const int cc2 = v2 ? c2 : 0;
    floatx4 t[10], u[10];
    if (s & 1) {  // lvl2 sources: streamed once, nontemporal
#pragma unroll
      for (int k = 0; k < 10; ++k) {
        t[k] = __builtin_nontemporal_load(Ng + (long)k * 125 + lane);
        u[k] = __builtin_nontemporal_load(Ng + (long)k * 125 + cc2);
      }
    } else {      // lvl1 sources: keep cache-resident (self pass reuses)
#pragma unroll
      for (int k = 0; k < 10; ++k) {
        t[k] = Ng[(long)k * 125 + lane];
        u[k] = Ng[(long)k * 125 + cc2];
      }
    }
    const floatx4 ts = (((t[0] + t[1]) + (t[2] + t[3])) + ((t[4] + t[5]) + (t[6] + t[7]))) + (t[8] + t[9]);
    const floatx4 us = (((u[0] + u[1]) + (u[2] + u[3])) + ((u[4] + u[5]) + (u[6] + u[7]))) + (u[8] + u[9]);
    const floatx4 m0 = ts * 0.1f;
    floatx4 m1 = us * 0.1f;
    if (!v2) m1 = (floatx4){0.f, 0.f, 0.f, 0.f};
    ushort4 o0, o1;
    o0.x = f2bf(m0.x); o0.y = f2bf(m0.y); o0.z = f2bf(m0.z); o0.w = f2bf(m0.w);
    o1.x = f2bf(m1.x); o1.y = f2bf(m1.y); o1.z = f2bf(m1.z); o1.w = f2bf(m1.w);
    const long og = (long)P.outRow[s] + r;
    A1v[og * 256 + 128 + lane] = o0;
    A1v[og * 256 + 128 + c2] = o1;
  }
}

// ---------------- agg1: H1 bf16 -> A2 [1792][512] bf16 (self | mean10) -------
__global__ __launch_bounds__(256) void agg1_pack(const ushort* __restrict__ H1, ushort* __restrict__ A2,
                                                 long total) {
  const long stride = (long)gridDim.x * 256;
  for (long idx = (long)blockIdx.x * 256 + threadIdx.x; idx < total; idx += stride) {
    const bool g1 = idx >= 32768, g2 = idx >= 65536;
    const long base = g2 ? 65536 : (g1 ? 32768 : 0);
    const int selfo = g2 ? 5632 : (g1 ? 2816 : 0);
    const int neigho = g2 ? 6912 : (g1 ? 3072 : 256);
    const int outo = g2 ? 512 : (g1 ? 256 : 0);
    const long li = idx - base;
    const long r = li >> 7;
    const int c = (int)(li & 127);
    const ushort4* H = (const ushort4*)H1;
    ushort4 ov;
    if (c < 64) {
      ov = H[((long)selfo + r) * 64 + c];
    } else {
      const int j = c - 64;
      float ax = 0.f, ay = 0.f, az = 0.f, aw = 0.f;
#pragma unroll
      for (int k = 0; k < 10; ++k) {
        const ushort4 v = H[((long)neigho + r * 10 + k) * 64 + j];
        ax += bf2f(v.x); ay += bf2f(v.y); az += bf2f(v.z); aw += bf2f(v.w);
      }
      ov.x = f2bf(ax * 0.1f); ov.y = f2bf(ay * 0.1f);
      ov.z = f2bf(az * 0.1f); ov.w = f2bf(aw * 0.1f);
    }
    ((ushort4*)A2)[((long)outo + r) * 128 + c] = ov;
  }
}

// ---------------- MFMA GEMM: C = relu(A[M,K]bf16 @ Bpacked[K,N]bf16) ---------
// A staged via global_load_lds with XOR-swizzled source; B fragment-linear.
template <int BM, int BN, int MI, int NI, bool OUT_BF16>
__global__ __launch_bounds__(256) void gemm_mfma(const ushort* __restrict__ A,
                                                 const ushort* __restrict__ Bp,
                                                 void* __restrict__ Cout, int K, int Nfull) {
  __shared__ ushort As[BM * 32];
  __shared__ ushort Bs[BN * 32];

  const int tid = threadIdx.x;
  const int wid = tid >> 6, l = tid & 63;
  const int wr = wid >> 1, wc = wid & 1;
  const int lr = l & 15, kg = l >> 4;
  const long row0 = (long)blockIdx.x * BM;
  const int n0 = blockIdx.y * BN;

  int aoff[MI], boff[NI];
#pragma unroll
  for (int mi = 0; mi < MI; ++mi) {
    const int row = wr * (MI * 16) + mi * 16 + lr;
    aoff[mi] = row * 64 + ((kg ^ ((row >> 1) & 3)) << 4);
  }
#pragma unroll
  for (int ni = 0; ni < NI; ++ni) {
    const int cell = kg * BN + wc * (NI * 16) + ni * 16 + lr;
    boff[ni] = cell << 4;
  }

  floatx4 acc[MI][NI];
#pragma unroll
  for (int mi = 0; mi < MI; ++mi)
#pragma unroll
    for (int ni = 0; ni < NI; ++ni) acc[mi][ni] = (floatx4){0.f, 0.f, 0.f, 0.f};

  const int ksteps = K >> 5;
  for (int ks = 0; ks < ksteps; ++ks) {
    const int k0 = ks << 5;
    __syncthreads();
#pragma unroll
    for (int it = 0; it < (BM * 64) / 4096; ++it) {
      const int o = it * 4096 + tid * 16;
      const int row = o >> 6;
      const int sw = (o >> 4) & 3;
      const int kgs = sw ^ ((row >> 1) & 3);
      const ushort* g = A + (row0 + row) * (size_t)K + (k0 + kgs * 8);
      gll16(g, (char*)As + it * 4096 + wid * 1024);
    }
#pragma unroll
    for (int it = 0; it < (BN * 64) / 4096; ++it) {
      const int cell = it * 256 + tid;
      const int bkg = cell / BN;
      const int n = cell & (BN - 1);
      const ushort* g = Bp + ((size_t)(ks * 4 + bkg) * Nfull + (n0 + n)) * 8;
      gll16(g, (char*)Bs + it * 4096 + wid * 1024);
    }
    __syncthreads();

    bhalf8 af[MI], bf[NI];
#pragma unroll
    for (int mi = 0; mi < MI; ++mi) af[mi] = *(const bhalf8*)((const char*)As + aoff[mi]);
#pragma unroll
    for (int ni = 0; ni < NI; ++ni) bf[ni] = *(const bhalf8*)((const char*)Bs + boff[ni]);
#pragma unroll
    for (int mi = 0; mi < MI; ++mi)
#pragma unroll
      for (int ni = 0; ni < NI; ++ni)
        acc[mi][ni] = __builtin_amdgcn_mfma_f32_16x16x32_bf16(af[mi], bf[ni], acc[mi][ni], 0, 0, 0);
  }

#pragma unroll
  for (int mi = 0; mi < MI; ++mi)
#pragma unroll
    for (int ni = 0; ni < NI; ++ni) {
      const floatx4 v = acc[mi][ni];
      const int gcol = n0 + wc * (NI * 16) + ni * 16 + lr;
#pragma unroll
      for (int r = 0; r < 4; ++r) {
        const long grow = row0 + wr * (MI * 16) + mi * 16 + kg * 4 + r;
        const float x = fmaxf(v[r], 0.f);
        if (OUT_BF16)
          ((ushort*)Cout)[grow * Nfull + gcol] = f2bf(x);
        else
          ((float*)Cout)[grow * Nfull + gcol] = x;
      }
    }
}

extern "C" void kernel_launch(void* const* d_in, const int* in_sizes, int n_in,
                              void* d_out, int out_size, void* d_ws, size_t ws_size,
                              hipStream_t stream) {
  const float* xsrc0 = (const float*)d_in[0];
  const float* xdst0 = (const float*)d_in[1];
  const float* xneg0 = (const float*)d_in[2];
  const float* xsrc1 = (const float*)d_in[3];
  const float* xdst1 = (const float*)d_in[4];
  const float* xneg1 = (const float*)d_in[5];
  const float* xsrc2 = (const float*)d_in[6];
  const float* xdst2 = (const float*)d_in[7];
  const float* xneg2 = (const float*)d_in[8];
  const float* W0 = (const float*)d_in[9];
  const float* W1 = (const float*)d_in[10];
  float* out = (float*)d_out;

  // workspace (ushorts), 16B aligned:
  ushort* A1 = (ushort*)d_ws;       // 19712*1024 = 20,185,088
  ushort* H1 = A1 + 20185088;       // 19712*256  =  5,046,272
  ushort* A2 = H1 + 5046272;        // 1792*512   =    917,504
  ushort* W0p = A2 + 917504;        // 262,144
  ushort* W1p = W0p + 262144;       // 65,536   (total ~53 MB)

  pack_w<<<dim3(1280), dim3(256), 0, stream>>>(W0, W1, W0p, W1p);

  // ---- layer0 aggregation (self cast + mean10), wave-per-row ----
  {
    AggP p;
    const float* selfs[6] = {xsrc0, xsrc1, xdst0, xdst1, xneg0, xneg1};
    const float* neighs[6] = {xsrc1, xsrc2, xdst1, xdst2, xneg1, xneg2};
    static const int rows[6] = {256, 2560, 256, 2560, 1280, 12800};
    static const int morder[6] = {0, 2, 4, 1, 3, 5};
    int cums = 0, orow = 0;
    for (int j = 0; j < 6; ++j) {
      p.selfp[j] = selfs[j];
      p.neigh[j] = neighs[j];
      cums += rows[j] / 16;
      p.selfEnd[j] = cums;           // {16,176,192,352,432,1232}
      p.outRow[j] = orow;
      orow += rows[j];
    }
    int cumm = 1232;
    for (int j = 0; j < 6; ++j) {
      const int sg = morder[j];
      p.meanSeg[j] = sg;
      cumm += rows[sg] / 4;
      p.meanEnd[j] = cumm;           // {1296,1360,1680,2320,2960,6160}
    }
    agg0_stream<<<dim3(6160), dim3(256), 0, stream>>>(p, A1);
  }

  // ---- layer0 GEMM: [19712,1024] @ [1024,256] -> H1 bf16 ----
  gemm_mfma<128, 128, 4, 4, true><<<dim3(154, 2), dim3(256), 0, stream>>>(A1, W0p, H1, 1024, 256);

  // ---- layer1 agg + pack: H1 -> A2 [1792][512] ----
  agg1_pack<<<dim3(896), dim3(256), 0, stream>>>(H1, A2, 229376);

  // ---- layer1 GEMM: [1792,512] @ [512,128] -> d_out fp32 ----
  gemm_mfma<64, 64, 2, 2, false><<<dim3(28, 2), dim3(256), 0, stream>>>(A2, W1p, out, 512, 128);
}

// Round 8
// 136.195 us; speedup vs baseline: 1.0748x; 1.0748x over previous
//
#include <hip/hip_runtime.h>

// ---------------------------------------------------------------------------
// GraphSAGE 2-layer forward, bf16 MFMA.
// Pipeline: prep (W-pack + mean10->M1 + pad) -> gemm0_hybrid (self fp32 + M1) ->
//           agg1_pack -> gemm1.
// Segments (rows): src0 256, src1 2560, dst0 256, dst1 2560, neg0 1280, neg1 12800
// Row offsets: src0@0 src1@256 dst0@2816 dst1@3072 neg0@5632 neg1@6912, tot 19712
// Logical A of layer0 (K=1024): [0,512)=self(500+12 pad), [512,1024)=mean(500+12 pad)
// M1 [19712][512] bf16 holds only the mean half.
// ---------------------------------------------------------------------------

typedef __attribute__((ext_vector_type(8))) short bhalf8;
typedef __attribute__((ext_vector_type(4))) float floatx4;

__device__ __forceinline__ ushort f2bf(float f) {
  uint32_t u = __float_as_uint(f);
  return (ushort)((u + 0x7fffu + ((u >> 16) & 1u)) >> 16);
}
__device__ __forceinline__ float bf2f(ushort u) {
  return __uint_as_float(((uint32_t)u) << 16);
}
__device__ __forceinline__ void gll16(const void* g, void* l) {
  __builtin_amdgcn_global_load_lds((const __attribute__((address_space(1))) void*)g,
                                   (__attribute__((address_space(3))) void*)l, 16, 0, 0);
}

// ------- prep: grid 11136 = 1280 (W pack) | 9625 (mean10) | 231 (M1 pad) ----
// W0p: [kstp(32)][kg(4)][n(256)][i(8)]; k<512 -> W0 row k (<500 valid),
//      k>=512 -> W0 row 500+(k-512) (<500 valid), else 0.
// W1p: [kstp(16)][kg(4)][n(128)][i(8)], K=512.
// Mean job: item = one output float4; blkEnd {125,1375,1500,2750,3375,9625}.
struct PrepP {
  const float* neigh[6];  // {xsrc1,xsrc2,xdst1,xdst2,xneg1,xneg2}
  int blkEnd[6];
  int outRow[6];          // {0,256,2816,3072,5632,6912}
};

__global__ __launch_bounds__(256) void prep(PrepP P, const float* __restrict__ W0,
                                            const float* __restrict__ W1,
                                            ushort* __restrict__ W0p, ushort* __restrict__ W1p,
                                            ushort* __restrict__ M1) {
  const int b = blockIdx.x, tid = threadIdx.x;
  if (b < 1280) {
    const int idx = b * 256 + tid;
    if (idx < 262144) {
      const int i = idx & 7, n = (idx >> 3) & 255, kgv = (idx >> 11) & 3, kstp = idx >> 13;
      const int k = kstp * 32 + kgv * 8 + i;
      int srcr;
      if (k < 512) srcr = (k < 500) ? k : -1;
      else { const int k2 = k - 512; srcr = (k2 < 500) ? 500 + k2 : -1; }
      W0p[idx] = (srcr >= 0) ? f2bf(W0[srcr * 256 + n]) : (ushort)0;
    } else {
      const int j = idx - 262144;
      const int i = j & 7, n = (j >> 3) & 127, kgv = (j >> 10) & 3, kstp = j >> 12;
      const int k = kstp * 32 + kgv * 8 + i;
      W1p[j] = f2bf(W1[k * 128 + n]);
    }
  } else if (b < 10905) {
    const int bb = b - 1280;
    int s = 0;
#pragma unroll
    for (int t = 0; t < 5; ++t) s = (bb >= P.blkEnd[t]) ? t + 1 : s;
    const int base = s ? P.blkEnd[s - 1] : 0;
    const int li = (bb - base) * 256 + tid;
    const int r = li / 125;  // magic-mul
    const int j = li - r * 125;
    const floatx4* __restrict__ Ng = (const floatx4*)P.neigh[s] + (long)r * 1250 + j;
    floatx4 t[10];
    if (s & 1) {  // level-2 sources: single-use -> nontemporal
#pragma unroll
      for (int k = 0; k < 10; ++k) t[k] = __builtin_nontemporal_load(Ng + (long)k * 125);
    } else {      // level-1 sources: re-read by gemm0 self staging -> keep cached
#pragma unroll
      for (int k = 0; k < 10; ++k) t[k] = Ng[(long)k * 125];
    }
    const floatx4 ts =
        (((t[0] + t[1]) + (t[2] + t[3])) + ((t[4] + t[5]) + (t[6] + t[7]))) + (t[8] + t[9]);
    const floatx4 m = ts * 0.1f;
    ushort4 o;
    o.x = f2bf(m.x); o.y = f2bf(m.y); o.z = f2bf(m.z); o.w = f2bf(m.w);
    ((ushort4*)M1)[((long)P.outRow[s] + r) * 128 + j] = o;
  } else {
    const int p = (b - 10905) * 256 + tid;  // < 59136 = 19712*3
    const int r = p / 3;
    const int sl = p - r * 3;
    ushort4 z; z.x = 0; z.y = 0; z.z = 0; z.w = 0;
    ((ushort4*)M1)[(long)r * 128 + 125 + sl] = z;
  }
}

// ------- gemm0_hybrid: H1 = relu([selfF32 | M1] @ W0p), 128x128 tile --------
// ks<16: self k-steps staged from fp32 inputs (reg-stage + cvt + swizzled ds_write)
// ks>=16: mean k-steps staged from M1 via global_load_lds (pre-swizzled source)
struct G0P {
  const float* selfp[6];  // {xsrc0,xsrc1,xdst0,xdst1,xneg0,xneg1}
  int tileEnd[6];         // 128-row tiles: {2,22,24,44,54,154}
};

__global__ __launch_bounds__(256) void gemm0_hybrid(G0P P, const ushort* __restrict__ M1,
                                                    const ushort* __restrict__ W0p,
                                                    ushort* __restrict__ H1) {
  __shared__ ushort As[128 * 32];  // 8 KB, row*64B, 16B slots kg ^ ((row>>1)&3)
  __shared__ ushort Bs[128 * 32];  // 8 KB, [kg(4)][n(128)][8]

  const int tid = threadIdx.x;
  const int wid = tid >> 6, l = tid & 63;
  const int wr = wid >> 1, wc = wid & 1;
  const int lr = l & 15, kg = l >> 4;

  const int bt = blockIdx.x;
  const int n0 = blockIdx.y * 128;
  int s = 0;
#pragma unroll
  for (int t = 0; t < 5; ++t) s = (bt >= P.tileEnd[t]) ? t + 1 : s;
  const int tb = s ? P.tileEnd[s - 1] : 0;
  const long lrow0 = (long)(bt - tb) * 128;
  const long row0 = (long)bt * 128;

  // self staging mapping: thread -> (row, 16-col half)
  const int srow = tid >> 1, half = tid & 1;
  const floatx4* __restrict__ selfF4 = (const floatx4*)P.selfp[s] + (lrow0 + srow) * 125;
  const int swr = (srow >> 1) & 3;
  const int kg0 = half * 2;

  int aoff[4], boff[4];
#pragma unroll
  for (int mi = 0; mi < 4; ++mi) {
    const int row = wr * 64 + mi * 16 + lr;
    aoff[mi] = row * 64 + ((kg ^ ((row >> 1) & 3)) << 4);
  }
#pragma unroll
  for (int ni = 0; ni < 4; ++ni) boff[ni] = (kg * 128 + wc * 64 + ni * 16 + lr) << 4;

  floatx4 acc[4][4];
#pragma unroll
  for (int mi = 0; mi < 4; ++mi)
#pragma unroll
    for (int ni = 0; ni < 4; ++ni) acc[mi][ni] = (floatx4){0.f, 0.f, 0.f, 0.f};

  for (int ks = 0; ks < 32; ++ks) {
    __syncthreads();  // previous iteration's LDS reads done
    if (ks < 16) {
      // self: A cols [ks*32, ks*32+32) = feature cols, this thread covers 16
      const int f0 = ks * 8 + half * 4;  // float4 index base
      floatx4 v[4];
#pragma unroll
      for (int q = 0; q < 4; ++q) {
        const int fi = f0 + q;
        v[q] = selfF4[(fi > 124) ? 124 : fi];
      }
      ushort h[16];
#pragma unroll
      for (int q = 0; q < 4; ++q) {
        const bool ok = (f0 + q) <= 124;
#pragma unroll
        for (int e = 0; e < 4; ++e) h[q * 4 + e] = ok ? f2bf(v[q][e]) : (ushort)0;
      }
      bhalf8 c0, c1;
#pragma unroll
      for (int e = 0; e < 8; ++e) { c0[e] = (short)h[e]; c1[e] = (short)h[8 + e]; }
      *(bhalf8*)((char*)As + srow * 64 + ((kg0 ^ swr) << 4)) = c0;
      *(bhalf8*)((char*)As + srow * 64 + (((kg0 + 1) ^ swr) << 4)) = c1;
    } else {
      const int k0 = (ks - 16) * 32;
#pragma unroll
      for (int it = 0; it < 2; ++it) {
        const int o = it * 4096 + tid * 16;
        const int row = o >> 6;
        const int sw = (o >> 4) & 3;
        const int kgs = sw ^ ((row >> 1) & 3);
        const ushort* g = M1 + (row0 + row) * (size_t)512 + (k0 + kgs * 8);
        gll16(g, (char*)As + it * 4096 + wid * 1024);
      }
    }
#pragma unroll
    for (int it = 0; it < 2; ++it) {
      const int cell = it * 256 + tid;
      const int bkg = cell >> 7;
      const int n = cell & 127;
      const ushort* g = W0p + ((size_t)(ks * 4 + bkg) * 256 + (n0 + n)) * 8;
      gll16(g, (char*)Bs + it * 4096 + wid * 1024);
    }
    __syncthreads();  // drains gll16 (vmcnt) + ds_writes (lgkm)

    bhalf8 af[4], bfr[4];
#pragma unroll
    for (int mi = 0; mi < 4; ++mi) af[mi] = *(const bhalf8*)((const char*)As + aoff[mi]);
#pragma unroll
    for (int ni = 0; ni < 4; ++ni) bfr[ni] = *(const bhalf8*)((const char*)Bs + boff[ni]);
#pragma unroll
    for (int mi = 0; mi < 4; ++mi)
#pragma unroll
      for (int ni = 0; ni < 4; ++ni)
        acc[mi][ni] = __builtin_amdgcn_mfma_f32_16x16x32_bf16(af[mi], bfr[ni], acc[mi][ni], 0, 0, 0);
  }

  // epilogue: relu + bf16 store. C/D: col = lane&15, row = (lane>>4)*4 + reg
#pragma unroll
  for (int mi = 0; mi < 4; ++mi)
#pragma unroll
    for (int ni = 0; ni < 4; ++ni) {
      const floatx4 v = acc[mi][ni];
      const int gcol = n0 + wc * 64 + ni * 16 + lr;
#pragma unroll
      for (int r = 0; r < 4; ++r) {
        const long grow = row0 + wr * 64 + mi * 16 + kg * 4 + r;
        H1[grow * 256 + gcol] = f2bf(fmaxf(v[r], 0.f));
      }
    }
}

// ---------------- agg1: H1 bf16 -> A2 [1792][512] bf16 (self | mean10) -------
__global__ __launch_bounds__(256) void agg1_pack(const ushort* __restrict__ H1, ushort* __restrict__ A2,
                                                 long total) {
  const long stride = (long)gridDim.x * 256;
  for (long idx = (long)blockIdx.x * 256 + threadIdx.x; idx < total; idx += stride) {
    const bool g1 = idx >= 32768, g2 = idx >= 65536;
    const long base = g2 ? 65536 : (g1 ? 32768 : 0);
    const int selfo = g2 ? 5632 : (g1 ? 2816 : 0);
    const int neigho = g2 ? 6912 : (g1 ? 3072 : 256);
    const int outo = g2 ? 512 : (g1 ? 256 : 0);
    const long li = idx - base;
    const long r = li >> 7;
    const int c = (int)(li & 127);
    const ushort4* H = (const ushort4*)H1;
    ushort4 ov;
    if (c < 64) {
      ov = H[((long)selfo + r) * 64 + c];
    } else {
      const int j = c - 64;
      float ax = 0.f, ay = 0.f, az = 0.f, aw = 0.f;
#pragma unroll
      for (int k = 0; k < 10; ++k) {
        const ushort4 v = H[((long)neigho + r * 10 + k) * 64 + j];
        ax += bf2f(v.x); ay += bf2f(v.y); az += bf2f(v.z); aw += bf2f(v.w);
      }
      ov.x = f2bf(ax * 0.1f); ov.y = f2bf(ay * 0.1f);
      ov.z = f2bf(az * 0.1f); ov.w = f2bf(aw * 0.1f);
    }
    ((ushort4*)A2)[((long)outo + r) * 128 + c] = ov;
  }
}

// ---------------- MFMA GEMM (layer1): C = relu(A @ Bpacked) ------------------
template <int BM, int BN, int MI, int NI, bool OUT_BF16>
__global__ __launch_bounds__(256) void gemm_mfma(const ushort* __restrict__ A,
                                                 const ushort* __restrict__ Bp,
                                                 void* __restrict__ Cout, int K, int Nfull) {
  __shared__ ushort As[BM * 32];
  __shared__ ushort Bs[BN * 32];

  const int tid = threadIdx.x;
  const int wid = tid >> 6, l = tid & 63;
  const int wr = wid >> 1, wc = wid & 1;
  const int lr = l & 15, kg = l >> 4;
  const long row0 = (long)blockIdx.x * BM;
  const int n0 = blockIdx.y * BN;

  int aoff[MI], boff[NI];
#pragma unroll
  for (int mi = 0; mi < MI; ++mi) {
    const int row = wr * (MI * 16) + mi * 16 + lr;
    aoff[mi] = row * 64 + ((kg ^ ((row >> 1) & 3)) << 4);
  }
#pragma unroll
  for (int ni = 0; ni < NI; ++ni) {
    const int cell = kg * BN + wc * (NI * 16) + ni * 16 + lr;
    boff[ni] = cell << 4;
  }

  floatx4 acc[MI][NI];
#pragma unroll
  for (int mi = 0; mi < MI; ++mi)
#pragma unroll
    for (int ni = 0; ni < NI; ++ni) acc[mi][ni] = (floatx4){0.f, 0.f, 0.f, 0.f};

  const int ksteps = K >> 5;
  for (int ks = 0; ks < ksteps; ++ks) {
    const int k0 = ks << 5;
    __syncthreads();
#pragma unroll
    for (int it = 0; it < (BM * 64) / 4096; ++it) {
      const int o = it * 4096 + tid * 16;
      const int row = o >> 6;
      const int sw = (o >> 4) & 3;
      const int kgs = sw ^ ((row >> 1) & 3);
      const ushort* g = A + (row0 + row) * (size_t)K + (k0 + kgs * 8);
      gll16(g, (char*)As + it * 4096 + wid * 1024);
    }
#pragma unroll
    for (int it = 0; it < (BN * 64) / 4096; ++it) {
      const int cell = it * 256 + tid;
      const int bkg = cell / BN;
      const int n = cell & (BN - 1);
      const ushort* g = Bp + ((size_t)(ks * 4 + bkg) * Nfull + (n0 + n)) * 8;
      gll16(g, (char*)Bs + it * 4096 + wid * 1024);
    }
    __syncthreads();

    bhalf8 af[MI], bf[NI];
#pragma unroll
    for (int mi = 0; mi < MI; ++mi) af[mi] = *(const bhalf8*)((const char*)As + aoff[mi]);
#pragma unroll
    for (int ni = 0; ni < NI; ++ni) bf[ni] = *(const bhalf8*)((const char*)Bs + boff[ni]);
#pragma unroll
    for (int mi = 0; mi < MI; ++mi)
#pragma unroll
      for (int ni = 0; ni < NI; ++ni)
        acc[mi][ni] = __builtin_amdgcn_mfma_f32_16x16x32_bf16(af[mi], bf[ni], acc[mi][ni], 0, 0, 0);
  }

#pragma unroll
  for (int mi = 0; mi < MI; ++mi)
#pragma unroll
    for (int ni = 0; ni < NI; ++ni) {
      const floatx4 v = acc[mi][ni];
      const int gcol = n0 + wc * (NI * 16) + ni * 16 + lr;
#pragma unroll
      for (int r = 0; r < 4; ++r) {
        const long grow = row0 + wr * (MI * 16) + mi * 16 + kg * 4 + r;
        const float x = fmaxf(v[r], 0.f);
        if (OUT_BF16)
          ((ushort*)Cout)[grow * Nfull + gcol] = f2bf(x);
        else
          ((float*)Cout)[grow * Nfull + gcol] = x;
      }
    }
}

extern "C" void kernel_launch(void* const* d_in, const int* in_sizes, int n_in,
                              void* d_out, int out_size, void* d_ws, size_t ws_size,
                              hipStream_t stream) {
  const float* xsrc0 = (const float*)d_in[0];
  const float* xdst0 = (const float*)d_in[1];
  const float* xneg0 = (const float*)d_in[2];
  const float* xsrc1 = (const float*)d_in[3];
  const float* xdst1 = (const float*)d_in[4];
  const float* xneg1 = (const float*)d_in[5];
  const float* xsrc2 = (const float*)d_in[6];
  const float* xdst2 = (const float*)d_in[7];
  const float* xneg2 = (const float*)d_in[8];
  const float* W0 = (const float*)d_in[9];
  const float* W1 = (const float*)d_in[10];
  float* out = (float*)d_out;

  // workspace (ushorts), 16B aligned:
  ushort* M1 = (ushort*)d_ws;       // 19712*512 = 10,092,544
  ushort* H1 = M1 + 10092544;       // 19712*256 =  5,046,272
  ushort* A2 = H1 + 5046272;        // 1792*512  =    917,504
  ushort* W0p = A2 + 917504;        // 262,144
  ushort* W1p = W0p + 262144;       // 65,536   (total ~33 MB)

  static const int rows[6] = {256, 2560, 256, 2560, 1280, 12800};

  // ---- prep: W pack + mean10 -> M1 + M1 pad ----
  {
    PrepP p;
    const float* neighs[6] = {xsrc1, xsrc2, xdst1, xdst2, xneg1, xneg2};
    int cumb = 0, orow = 0;
    for (int j = 0; j < 6; ++j) {
      p.neigh[j] = neighs[j];
      cumb += rows[j] * 125 / 256;
      p.blkEnd[j] = cumb;   // {125,1375,1500,2750,3375,9625}
      p.outRow[j] = orow;
      orow += rows[j];
    }
    prep<<<dim3(11136), dim3(256), 0, stream>>>(p, W0, W1, W0p, W1p, M1);
  }

  // ---- layer0 GEMM (hybrid A): [19712, self|mean] @ W0p -> H1 bf16 ----
  {
    G0P g;
    const float* selfs[6] = {xsrc0, xsrc1, xdst0, xdst1, xneg0, xneg1};
    int cumt = 0;
    for (int j = 0; j < 6; ++j) {
      g.selfp[j] = selfs[j];
      cumt += rows[j] / 128;
      g.tileEnd[j] = cumt;  // {2,22,24,44,54,154}
    }
    gemm0_hybrid<<<dim3(154, 2), dim3(256), 0, stream>>>(g, M1, W0p, H1);
  }

  // ---- layer1 agg + pack: H1 -> A2 [1792][512] ----
  agg1_pack<<<dim3(896), dim3(256), 0, stream>>>(H1, A2, 229376);

  // ---- layer1 GEMM: [1792,512] @ [512,128] -> d_out fp32 ----
  gemm_mfma<64, 64, 2, 2, false><<<dim3(28, 2), dim3(256), 0, stream>>>(A2, W1p, out, 512, 128);
}

// Round 9
// 120.601 us; speedup vs baseline: 1.2137x; 1.1293x over previous
//
#include <hip/hip_runtime.h>

// ---------------------------------------------------------------------------
// GraphSAGE 2-layer forward, bf16 MFMA.
// Pipeline: misc (W pack + pads) -> mean_stream (mean10 -> M1, lvl1 bf16 -> S1)
//           -> gemm0_hybrid -> agg1_pack -> gemm1.
// Output rows: src0@0(256) src1@256(2560) dst0@2816(256) dst1@3072(2560)
//              neg0@5632(1280) neg1@6912(12800), tot 19712
// Layer0 logical A (K=1024): [0,512)=self(500+pad), [512,1024)=mean(500+pad)
// M1 [19712][512] bf16 = mean half. S1 [17920][512] bf16 = lvl1 self rows
// (src1|dst1|neg1 at row offsets 0/2560/5120), cols [500,512) zero.
// ---------------------------------------------------------------------------

typedef __attribute__((ext_vector_type(8))) short bhalf8;
typedef __attribute__((ext_vector_type(4))) float floatx4;

__device__ __forceinline__ ushort f2bf(float f) {
  uint32_t u = __float_as_uint(f);
  return (ushort)((u + 0x7fffu + ((u >> 16) & 1u)) >> 16);
}
__device__ __forceinline__ float bf2f(ushort u) {
  return __uint_as_float(((uint32_t)u) << 16);
}
__device__ __forceinline__ void gll16(const void* g, void* l) {
  __builtin_amdgcn_global_load_lds((const __attribute__((address_space(1))) void*)g,
                                   (__attribute__((address_space(3))) void*)l, 16, 0, 0);
}

// ------- misc: grid 1721 = 1280 (W pack) | 231 (M1 pad) | 210 (S1 pad) ------
__global__ __launch_bounds__(256) void misc_k(const float* __restrict__ W0, const float* __restrict__ W1,
                                              ushort* __restrict__ W0p, ushort* __restrict__ W1p,
                                              ushort* __restrict__ M1, ushort* __restrict__ S1) {
  const int b = blockIdx.x, tid = threadIdx.x;
  if (b < 1280) {
    const int idx = b * 256 + tid;
    if (idx < 262144) {  // W0p: [kstp(32)][kg(4)][n(256)][i(8)]
      const int i = idx & 7, n = (idx >> 3) & 255, kgv = (idx >> 11) & 3, kstp = idx >> 13;
      const int k = kstp * 32 + kgv * 8 + i;
      int srcr;
      if (k < 512) srcr = (k < 500) ? k : -1;
      else { const int k2 = k - 512; srcr = (k2 < 500) ? 500 + k2 : -1; }
      W0p[idx] = (srcr >= 0) ? f2bf(W0[srcr * 256 + n]) : (ushort)0;
    } else {             // W1p: [kstp(16)][kg(4)][n(128)][i(8)]
      const int j = idx - 262144;
      const int i = j & 7, n = (j >> 3) & 127, kgv = (j >> 10) & 3, kstp = j >> 12;
      const int k = kstp * 32 + kgv * 8 + i;
      W1p[j] = f2bf(W1[k * 128 + n]);
    }
  } else if (b < 1511) {  // M1 pad cols [125,128) f4 over 19712 rows
    const int p = (b - 1280) * 256 + tid;  // < 59136
    const int r = p / 3, sl = p - r * 3;
    ushort4 z; z.x = 0; z.y = 0; z.z = 0; z.w = 0;
    ((ushort4*)M1)[(long)r * 128 + 125 + sl] = z;
  } else {                // S1 pad cols [125,128) f4 over 17920 rows
    const int p = (b - 1511) * 256 + tid;  // < 53760
    const int r = p / 3, sl = p - r * 3;
    ushort4 z; z.x = 0; z.y = 0; z.z = 0; z.w = 0;
    ((ushort4*)S1)[(long)r * 128 + 125 + sl] = z;
  }
}

// ------- mean_stream: items = output f4 cols, order lvl2 then lvl1 ----------
// order slots p=0..5 -> segs {src1o,dst1o,neg1o from lvl2; src0o,dst0o,neg0o from lvl1}
// itemEnd {320000,640000,2240000,2272000,2304000,2464000}; HALF=1232000.
// Thread does items i and i+HALF (item1 always lvl2 -> NT loads).
// lvl1 items (p>=3) also side-write bf16 rows into S1.
struct MSP {
  const float* src[6];   // {xsrc2,xdst2,xneg2,xsrc1,xdst1,xneg1}
  long itemEnd[6];
  int outRow[6];         // {256,3072,6912,0,2816,5632}
  int s1Off[6];          // {0,0,0,0,2560,5120}
};

__global__ __launch_bounds__(256, 4) void mean_stream(MSP P, ushort* __restrict__ M1,
                                                      ushort* __restrict__ S1) {
  long i = (long)blockIdx.x * 256 + threadIdx.x;
  if (i >= 1232000) i = 1231999;
  // item1 (always lvl2)
  int p1 = 0;
#pragma unroll
  for (int t = 0; t < 2; ++t) p1 = (i >= P.itemEnd[t]) ? t + 1 : p1;
  const long b1 = p1 ? P.itemEnd[p1 - 1] : 0;
  const int l1 = (int)(i - b1);
  const int r1 = l1 / 125, j1 = l1 - r1 * 125;
  const floatx4* __restrict__ sp1 = (const floatx4*)P.src[p1] + (long)r1 * 1250 + j1;
  // item2
  const long i2 = i + 1232000;
  int p2 = 2;
#pragma unroll
  for (int t = 2; t < 5; ++t) p2 = (i2 >= P.itemEnd[t]) ? t + 1 : p2;
  const long b2 = P.itemEnd[p2 - 1];
  const int l2 = (int)(i2 - b2);
  const int r2 = l2 / 125, j2 = l2 - r2 * 125;
  const floatx4* __restrict__ sp2 = (const floatx4*)P.src[p2] + (long)r2 * 1250 + j2;

  floatx4 t1[10], t2[10];
#pragma unroll
  for (int k = 0; k < 10; ++k) t1[k] = __builtin_nontemporal_load(sp1 + (long)k * 125);
  const bool lvl1 = p2 >= 3;
  if (!lvl1) {
#pragma unroll
    for (int k = 0; k < 10; ++k) t2[k] = __builtin_nontemporal_load(sp2 + (long)k * 125);
  } else {
#pragma unroll
    for (int k = 0; k < 10; ++k) t2[k] = sp2[(long)k * 125];
  }

  const floatx4 a1 =
      ((((t1[0] + t1[1]) + (t1[2] + t1[3])) + ((t1[4] + t1[5]) + (t1[6] + t1[7]))) + (t1[8] + t1[9])) * 0.1f;
  ushort4 o1;
  o1.x = f2bf(a1.x); o1.y = f2bf(a1.y); o1.z = f2bf(a1.z); o1.w = f2bf(a1.w);
  ((ushort4*)M1)[((long)P.outRow[p1] + r1) * 128 + j1] = o1;

  if (lvl1) {  // side-write bf16 casts of the 10 lvl1 rows into S1
    const long srow = (long)P.s1Off[p2] + (long)r2 * 10;
#pragma unroll
    for (int k = 0; k < 10; ++k) {
      ushort4 c;
      c.x = f2bf(t2[k].x); c.y = f2bf(t2[k].y); c.z = f2bf(t2[k].z); c.w = f2bf(t2[k].w);
      ((ushort4*)S1)[(srow + k) * 128 + j2] = c;
    }
  }
  const floatx4 a2 =
      ((((t2[0] + t2[1]) + (t2[2] + t2[3])) + ((t2[4] + t2[5]) + (t2[6] + t2[7]))) + (t2[8] + t2[9])) * 0.1f;
  ushort4 o2;
  o2.x = f2bf(a2.x); o2.y = f2bf(a2.y); o2.z = f2bf(a2.z); o2.w = f2bf(a2.w);
  ((ushort4*)M1)[((long)P.outRow[p2] + r2) * 128 + j2] = o2;
}

// ------- gemm0_hybrid: H1 = relu([self | M1] @ W0p), 128x128 tile -----------
// ks<16 self: even segs (lvl0) from fp32 + cvt; odd segs (lvl1) from S1 bf16.
// ks>=16 mean: from M1 via global_load_lds (pre-swizzled source).
struct G0P {
  const void* selfp[6];  // {xsrc0, S1+0, xdst0, S1+2560*512, xneg0, S1+5120*512}
  int tileEnd[6];        // {2,22,24,44,54,154}
};

__global__ __launch_bounds__(256) void gemm0_hybrid(G0P P, const ushort* __restrict__ M1,
                                                    const ushort* __restrict__ W0p,
                                                    ushort* __restrict__ H1) {
  __shared__ ushort As[128 * 32];
  __shared__ ushort Bs[128 * 32];

  const int tid = threadIdx.x;
  const int wid = tid >> 6, l = tid & 63;
  const int wr = wid >> 1, wc = wid & 1;
  const int lr = l & 15, kg = l >> 4;

  const int bt = blockIdx.x;
  const int n0 = blockIdx.y * 128;
  int s = 0;
#pragma unroll
  for (int t = 0; t < 5; ++t) s = (bt >= P.tileEnd[t]) ? t + 1 : s;
  const int tb = s ? P.tileEnd[s - 1] : 0;
  const long lrow0 = (long)(bt - tb) * 128;
  const long row0 = (long)bt * 128;

  const int srow = tid >> 1, half = tid & 1;
  const floatx4* __restrict__ selfF4 = (const floatx4*)P.selfp[s] + (lrow0 + srow) * 125;
  const ushort* __restrict__ selfB = (const ushort*)P.selfp[s] + (lrow0 + srow) * 512;
  const int swr = (srow >> 1) & 3;
  const int kg0 = half * 2;

  int aoff[4], boff[4];
#pragma unroll
  for (int mi = 0; mi < 4; ++mi) {
    const int row = wr * 64 + mi * 16 + lr;
    aoff[mi] = row * 64 + ((kg ^ ((row >> 1) & 3)) << 4);
  }
#pragma unroll
  for (int ni = 0; ni < 4; ++ni) boff[ni] = (kg * 128 + wc * 64 + ni * 16 + lr) << 4;

  floatx4 acc[4][4];
#pragma unroll
  for (int mi = 0; mi < 4; ++mi)
#pragma unroll
    for (int ni = 0; ni < 4; ++ni) acc[mi][ni] = (floatx4){0.f, 0.f, 0.f, 0.f};

  for (int ks = 0; ks < 32; ++ks) {
    __syncthreads();
    if (ks < 16) {
      bhalf8 c0, c1;
      if (!(s & 1)) {  // lvl0: fp32 + cvt
        const int f0 = ks * 8 + half * 4;
        floatx4 v[4];
#pragma unroll
        for (int q = 0; q < 4; ++q) {
          const int fi = f0 + q;
          v[q] = selfF4[(fi > 124) ? 124 : fi];
        }
        ushort h[16];
#pragma unroll
        for (int q = 0; q < 4; ++q) {
          const bool ok = (f0 + q) <= 124;
#pragma unroll
          for (int e = 0; e < 4; ++e) h[q * 4 + e] = ok ? f2bf(v[q][e]) : (ushort)0;
        }
#pragma unroll
        for (int e = 0; e < 8; ++e) { c0[e] = (short)h[e]; c1[e] = (short)h[8 + e]; }
      } else {         // lvl1: S1 bf16 direct (zero-padded)
        const int u0 = (ks * 8 + half * 4) * 4;  // ushort col
        c0 = *(const bhalf8*)(selfB + u0);
        c1 = *(const bhalf8*)(selfB + u0 + 8);
      }
      *(bhalf8*)((char*)As + srow * 64 + ((kg0 ^ swr) << 4)) = c0;
      *(bhalf8*)((char*)As + srow * 64 + (((kg0 + 1) ^ swr) << 4)) = c1;
    } else {
      const int k0 = (ks - 16) * 32;
#pragma unroll
      for (int it = 0; it < 2; ++it) {
        const int o = it * 4096 + tid * 16;
        const int row = o >> 6;
        const int sw = (o >> 4) & 3;
        const int kgs = sw ^ ((row >> 1) & 3);
        const ushort* g = M1 + (row0 + row) * (size_t)512 + (k0 + kgs * 8);
        gll16(g, (char*)As + it * 4096 + wid * 1024);
      }
    }
#pragma unroll
    for (int it = 0; it < 2; ++it) {
      const int cell = it * 256 + tid;
      const int bkg = cell >> 7;
      const int n = cell & 127;
      const ushort* g = W0p + ((size_t)(ks * 4 + bkg) * 256 + (n0 + n)) * 8;
      gll16(g, (char*)Bs + it * 4096 + wid * 1024);
    }
    __syncthreads();

    bhalf8 af[4], bfr[4];
#pragma unroll
    for (int mi = 0; mi < 4; ++mi) af[mi] = *(const bhalf8*)((const char*)As + aoff[mi]);
#pragma unroll
    for (int ni = 0; ni < 4; ++ni) bfr[ni] = *(const bhalf8*)((const char*)Bs + boff[ni]);
#pragma unroll
    for (int mi = 0; mi < 4; ++mi)
#pragma unroll
      for (int ni = 0; ni < 4; ++ni)
        acc[mi][ni] = __builtin_amdgcn_mfma_f32_16x16x32_bf16(af[mi], bfr[ni], acc[mi][ni], 0, 0, 0);
  }

#pragma unroll
  for (int mi = 0; mi < 4; ++mi)
#pragma unroll
    for (int ni = 0; ni < 4; ++ni) {
      const floatx4 v = acc[mi][ni];
      const int gcol = n0 + wc * 64 + ni * 16 + lr;
#pragma unroll
      for (int r = 0; r < 4; ++r) {
        const long grow = row0 + wr * 64 + mi * 16 + kg * 4 + r;
        H1[grow * 256 + gcol] = f2bf(fmaxf(v[r], 0.f));
      }
    }
}

// ---------------- agg1: H1 bf16 -> A2 [1792][512] bf16 (self | mean10) -------
__global__ __launch_bounds__(256) void agg1_pack(const ushort* __restrict__ H1, ushort* __restrict__ A2,
                                                 long total) {
  const long stride = (long)gridDim.x * 256;
  for (long idx = (long)blockIdx.x * 256 + threadIdx.x; idx < total; idx += stride) {
    const bool g1 = idx >= 32768, g2 = idx >= 65536;
    const long base = g2 ? 65536 : (g1 ? 32768 : 0);
    const int selfo = g2 ? 5632 : (g1 ? 2816 : 0);
    const int neigho = g2 ? 6912 : (g1 ? 3072 : 256);
    const int outo = g2 ? 512 : (g1 ? 256 : 0);
    const long li = idx - base;
    const long r = li >> 7;
    const int c = (int)(li & 127);
    const ushort4* H = (const ushort4*)H1;
    ushort4 ov;
    if (c < 64) {
      ov = H[((long)selfo + r) * 64 + c];
    } else {
      const int j = c - 64;
      float ax = 0.f, ay = 0.f, az = 0.f, aw = 0.f;
#pragma unroll
      for (int k = 0; k < 10; ++k) {
        const ushort4 v = H[((long)neigho + r * 10 + k) * 64 + j];
        ax += bf2f(v.x); ay += bf2f(v.y); az += bf2f(v.z); aw += bf2f(v.w);
      }
      ov.x = f2bf(ax * 0.1f); ov.y = f2bf(ay * 0.1f);
      ov.z = f2bf(az * 0.1f); ov.w = f2bf(aw * 0.1f);
    }
    ((ushort4*)A2)[((long)outo + r) * 128 + c] = ov;
  }
}

// ---------------- MFMA GEMM (layer1): C = relu(A @ Bpacked) ------------------
template <int BM, int BN, int MI, int NI, bool OUT_BF16>
__global__ __launch_bounds__(256) void gemm_mfma(const ushort* __restrict__ A,
                                                 const ushort* __restrict__ Bp,
                                                 void* __restrict__ Cout, int K, int Nfull) {
  __shared__ ushort As[BM * 32];
  __shared__ ushort Bs[BN * 32];

  const int tid = threadIdx.x;
  const int wid = tid >> 6, l = tid & 63;
  const int wr = wid >> 1, wc = wid & 1;
  const int lr = l & 15, kg = l >> 4;
  const long row0 = (long)blockIdx.x * BM;
  const int n0 = blockIdx.y * BN;

  int aoff[MI], boff[NI];
#pragma unroll
  for (int mi = 0; mi < MI; ++mi) {
    const int row = wr * (MI * 16) + mi * 16 + lr;
    aoff[mi] = row * 64 + ((kg ^ ((row >> 1) & 3)) << 4);
  }
#pragma unroll
  for (int ni = 0; ni < NI; ++ni) {
    const int cell = kg * BN + wc * (NI * 16) + ni * 16 + lr;
    boff[ni] = cell << 4;
  }

  floatx4 acc[MI][NI];
#pragma unroll
  for (int mi = 0; mi < MI; ++mi)
#pragma unroll
    for (int ni = 0; ni < NI; ++ni) acc[mi][ni] = (floatx4){0.f, 0.f, 0.f, 0.f};

  const int ksteps = K >> 5;
  for (int ks = 0; ks < ksteps; ++ks) {
    const int k0 = ks << 5;
    __syncthreads();
#pragma unroll
    for (int it = 0; it < (BM * 64) / 4096; ++it) {
      const int o = it * 4096 + tid * 16;
      const int row = o >> 6;
      const int sw = (o >> 4) & 3;
      const int kgs = sw ^ ((row >> 1) & 3);
      const ushort* g = A + (row0 + row) * (size_t)K + (k0 + kgs * 8);
      gll16(g, (char*)As + it * 4096 + wid * 1024);
    }
#pragma unroll
    for (int it = 0; it < (BN * 64) / 4096; ++it) {
      const int cell = it * 256 + tid;
      const int bkg = cell / BN;
      const int n = cell & (BN - 1);
      const ushort* g = Bp + ((size_t)(ks * 4 + bkg) * Nfull + (n0 + n)) * 8;
      gll16(g, (char*)Bs + it * 4096 + wid * 1024);
    }
    __syncthreads();

    bhalf8 af[MI], bf[NI];
#pragma unroll
    for (int mi = 0; mi < MI; ++mi) af[mi] = *(const bhalf8*)((const char*)As + aoff[mi]);
#pragma unroll
    for (int ni = 0; ni < NI; ++ni) bf[ni] = *(const bhalf8*)((const char*)Bs + boff[ni]);
#pragma unroll
    for (int mi = 0; mi < MI; ++mi)
#pragma unroll
      for (int ni = 0; ni < NI; ++ni)
        acc[mi][ni] = __builtin_amdgcn_mfma_f32_16x16x32_bf16(af[mi], bf[ni], acc[mi][ni], 0, 0, 0);
  }

#pragma unroll
  for (int mi = 0; mi < MI; ++mi)
#pragma unroll
    for (int ni = 0; ni < NI; ++ni) {
      const floatx4 v = acc[mi][ni];
      const int gcol = n0 + wc * (NI * 16) + ni * 16 + lr;
#pragma unroll
      for (int r = 0; r < 4; ++r) {
        const long grow = row0 + wr * (MI * 16) + mi * 16 + kg * 4 + r;
        const float x = fmaxf(v[r], 0.f);
        if (OUT_BF16)
          ((ushort*)Cout)[grow * Nfull + gcol] = f2bf(x);
        else
          ((float*)Cout)[grow * Nfull + gcol] = x;
      }
    }
}

extern "C" void kernel_launch(void* const* d_in, const int* in_sizes, int n_in,
                              void* d_out, int out_size, void* d_ws, size_t ws_size,
                              hipStream_t stream) {
  const float* xsrc0 = (const float*)d_in[0];
  const float* xdst0 = (const float*)d_in[1];
  const float* xneg0 = (const float*)d_in[2];
  const float* xsrc1 = (const float*)d_in[3];
  const float* xdst1 = (const float*)d_in[4];
  const float* xneg1 = (const float*)d_in[5];
  const float* xsrc2 = (const float*)d_in[6];
  const float* xdst2 = (const float*)d_in[7];
  const float* xneg2 = (const float*)d_in[8];
  const float* W0 = (const float*)d_in[9];
  const float* W1 = (const float*)d_in[10];
  float* out = (float*)d_out;

  // workspace (ushorts), 16B aligned:
  ushort* M1 = (ushort*)d_ws;        // 19712*512 = 10,092,544
  ushort* S1 = M1 + 10092544;        // 17920*512 =  9,175,040
  ushort* H1 = S1 + 9175040;         // 19712*256 =  5,046,272
  ushort* A2 = H1 + 5046272;         // 1792*512  =    917,504
  ushort* W0p = A2 + 917504;         // 262,144
  ushort* W1p = W0p + 262144;        // 65,536   (total ~51 MB)

  misc_k<<<dim3(1721), dim3(256), 0, stream>>>(W0, W1, W0p, W1p, M1, S1);

  // ---- mean stream (lvl2 first, lvl1 last + S1 side-write) ----
  {
    MSP p;
    const float* srcs[6] = {xsrc2, xdst2, xneg2, xsrc1, xdst1, xneg1};
    static const long itemEnd[6] = {320000, 640000, 2240000, 2272000, 2304000, 2464000};
    static const int outRow[6] = {256, 3072, 6912, 0, 2816, 5632};
    static const int s1Off[6] = {0, 0, 0, 0, 2560, 5120};
    for (int j = 0; j < 6; ++j) {
      p.src[j] = srcs[j];
      p.itemEnd[j] = itemEnd[j];
      p.outRow[j] = outRow[j];
      p.s1Off[j] = s1Off[j];
    }
    mean_stream<<<dim3(4813), dim3(256), 0, stream>>>(p, M1, S1);
  }

  // ---- layer0 GEMM (hybrid A) ----
  {
    G0P g;
    g.selfp[0] = xsrc0;
    g.selfp[1] = S1;
    g.selfp[2] = xdst0;
    g.selfp[3] = S1 + (size_t)2560 * 512;
    g.selfp[4] = xneg0;
    g.selfp[5] = S1 + (size_t)5120 * 512;
    static const int tileEnd[6] = {2, 22, 24, 44, 54, 154};
    for (int j = 0; j < 6; ++j) g.tileEnd[j] = tileEnd[j];
    gemm0_hybrid<<<dim3(154, 2), dim3(256), 0, stream>>>(g, M1, W0p, H1);
  }

  // ---- layer1 agg + pack ----
  agg1_pack<<<dim3(896), dim3(256), 0, stream>>>(H1, A2, 229376);

  // ---- layer1 GEMM ----
  gemm_mfma<64, 64, 2, 2, false><<<dim3(28, 2), dim3(256), 0, stream>>>(A2, W1p, out, 512, 128);
}